// Round 13
// baseline (687.503 us; speedup 1.0000x reference)
//
#include <hip/hip_runtime.h>
#include <hip/hip_bf16.h>

// Problem constants
constexpr int kL  = 2048;   // sequence length
constexpr int kD  = 64;     // head dim
constexpr int kBH = 64;     // B*H = 4*16
constexpr size_t kAttnOff = (size_t)kBH * kL * kD * 2;  // output elems before attn

typedef __bf16 bf16x8 __attribute__((ext_vector_type(8)));
typedef __bf16 bf16x4 __attribute__((ext_vector_type(4)));
typedef float  f32x4  __attribute__((ext_vector_type(4)));
typedef unsigned int u32x4 __attribute__((ext_vector_type(4)));

static __device__ inline bf16x8 neg8(bf16x8 v) {
  u32x4 t = __builtin_bit_cast(u32x4, v);
  t ^= 0x80008000u;
  return __builtin_bit_cast(bf16x8, t);
}

static __device__ inline bf16x8 pack8(const float4& a, const float4& b) {
  bf16x8 p;
  p[0]=(__bf16)a.x; p[1]=(__bf16)a.y; p[2]=(__bf16)a.z; p[3]=(__bf16)a.w;
  p[4]=(__bf16)b.x; p[5]=(__bf16)b.y; p[6]=(__bf16)b.z; p[7]=(__bf16)b.w;
  return p;
}

// Async 16B global -> LDS (direct, no VGPR roundtrip). LDS dest is
// wave-uniform base + lane*16 (tid*16 pattern satisfies this).
static __device__ inline void gl_lds16(char* l, const char* g) {
  __builtin_amdgcn_global_load_lds(
      (const __attribute__((address_space(1))) void*)g,
      (__attribute__((address_space(3))) void*)l, 16, 0, 0);
}

// ---------------------------------------------------------------------------
// Merged prep kernel: per (bh, 64-k chunk):
//  - kb tiles: K bf16, XOR-swizzled, tile (bh,kb)=8KB at (bh*32+kb)*8192;
//    element (krow, d) at byte krow*128 + ((d*2) ^ ((krow&7)<<4)).
//  - vt tiles: V^T bf16, swizzled; element (d, k) at byte
//    d*128 + ((k*2) ^ ((d&7)<<4)).
// ---------------------------------------------------------------------------
__global__ __launch_bounds__(256) void prep_all_kernel(
    const float* __restrict__ kr_g, const float* __restrict__ ki_g,
    const float* __restrict__ vr_g, const float* __restrict__ vi_g,
    __hip_bfloat16* __restrict__ kb_r, __hip_bfloat16* __restrict__ kb_i,
    __hip_bfloat16* __restrict__ vt_r, __hip_bfloat16* __restrict__ vt_i)
{
  __shared__ __align__(16) char lds_raw[2 * 8192];
  char* tr = lds_raw;
  char* ti = lds_raw + 8192;

  const int tid = threadIdx.x;
  const int bh  = blockIdx.x >> 5;
  const int kb  = blockIdx.x & 31;
  const int k0  = kb * 64;
  const size_t tb = ((size_t)bh * 32 + kb) * 8192;

  const int row = tid >> 2;
  const int d0  = (tid & 3) << 4;
  const size_t gb = ((size_t)bh * kL + k0 + row) * kD + d0;
  const int swz = (row & 7) << 4;

  // ---- K -> swizzled bf16 tiles (direct global write) ----
  {
    float4 x0 = *(const float4*)(kr_g + gb);
    float4 x1 = *(const float4*)(kr_g + gb + 4);
    float4 x2 = *(const float4*)(kr_g + gb + 8);
    float4 x3 = *(const float4*)(kr_g + gb + 12);
    *(bf16x8*)((char*)kb_r + tb + row * 128 + ((d0 * 2) ^ swz))      = pack8(x0, x1);
    *(bf16x8*)((char*)kb_r + tb + row * 128 + ((d0 * 2 + 16) ^ swz)) = pack8(x2, x3);
    float4 y0 = *(const float4*)(ki_g + gb);
    float4 y1 = *(const float4*)(ki_g + gb + 4);
    float4 y2 = *(const float4*)(ki_g + gb + 8);
    float4 y3 = *(const float4*)(ki_g + gb + 12);
    *(bf16x8*)((char*)kb_i + tb + row * 128 + ((d0 * 2) ^ swz))      = pack8(y0, y1);
    *(bf16x8*)((char*)kb_i + tb + row * 128 + ((d0 * 2 + 16) ^ swz)) = pack8(y2, y3);
  }

  // ---- V: stage swizzled in LDS, gather columns, write swizzled vt tiles ----
  {
    float4 x0 = *(const float4*)(vr_g + gb);
    float4 x1 = *(const float4*)(vr_g + gb + 4);
    float4 x2 = *(const float4*)(vr_g + gb + 8);
    float4 x3 = *(const float4*)(vr_g + gb + 12);
    *(bf16x8*)(tr + row * 128 + ((d0 * 2) ^ swz))      = pack8(x0, x1);
    *(bf16x8*)(tr + row * 128 + ((d0 * 2 + 16) ^ swz)) = pack8(x2, x3);
    float4 y0 = *(const float4*)(vi_g + gb);
    float4 y1 = *(const float4*)(vi_g + gb + 4);
    float4 y2 = *(const float4*)(vi_g + gb + 8);
    float4 y3 = *(const float4*)(vi_g + gb + 12);
    *(bf16x8*)(ti + row * 128 + ((d0 * 2) ^ swz))      = pack8(y0, y1);
    *(bf16x8*)(ti + row * 128 + ((d0 * 2 + 16) ^ swz)) = pack8(y2, y3);
  }
  __syncthreads();
  {
    const int d  = tid >> 2;         // 0..63
    const int kc = (tid & 3) << 4;   // 0,16,32,48
    char* outr = (char*)vt_r + tb + d * 128;
    char* outi = (char*)vt_i + tb + d * 128;
    const int oswz = (d & 7) << 4;
    bf16x8 pr0, pr1, pi0, pi1;
#pragma unroll
    for (int j = 0; j < 8; ++j) {
      const int k1 = kc + j;
      const int k2 = kc + 8 + j;
      const int b1 = k1 * 128 + ((d * 2) ^ ((k1 & 7) << 4));
      const int b2 = k2 * 128 + ((d * 2) ^ ((k2 & 7) << 4));
      pr0[j] = *(const __bf16*)(tr + b1);
      pr1[j] = *(const __bf16*)(tr + b2);
      pi0[j] = *(const __bf16*)(ti + b1);
      pi1[j] = *(const __bf16*)(ti + b2);
    }
    *(bf16x8*)(outr + ((kc * 2) ^ oswz))      = pr0;
    *(bf16x8*)(outr + ((kc * 2 + 16) ^ oswz)) = pr1;
    *(bf16x8*)(outi + ((kc * 2) ^ oswz))      = pi0;
    *(bf16x8*)(outi + ((kc * 2 + 16) ^ oswz)) = pi1;
  }
}

// ---------------------------------------------------------------------------
// Prep-K / Prep-V kernels for the time-shared fallback path (R12-proven).
// ---------------------------------------------------------------------------
__global__ __launch_bounds__(256) void prep_k_kernel(
    const float* __restrict__ kr_g, const float* __restrict__ ki_g,
    __hip_bfloat16* __restrict__ kb_r, __hip_bfloat16* __restrict__ kb_i)
{
  const int tid = threadIdx.x;
  const int bh  = blockIdx.x >> 5;
  const int kb  = blockIdx.x & 31;
  const int k0  = kb * 64;
  const size_t tb = ((size_t)bh * 32 + kb) * 8192;

  const int row = tid >> 2;
  const int d0  = (tid & 3) << 4;
  const size_t gb = ((size_t)bh * kL + k0 + row) * kD + d0;
  const int swz = (row & 7) << 4;

  float4 x0 = *(const float4*)(kr_g + gb);
  float4 x1 = *(const float4*)(kr_g + gb + 4);
  float4 x2 = *(const float4*)(kr_g + gb + 8);
  float4 x3 = *(const float4*)(kr_g + gb + 12);
  *(bf16x8*)((char*)kb_r + tb + row * 128 + ((d0 * 2) ^ swz))      = pack8(x0, x1);
  *(bf16x8*)((char*)kb_r + tb + row * 128 + ((d0 * 2 + 16) ^ swz)) = pack8(x2, x3);
  float4 y0 = *(const float4*)(ki_g + gb);
  float4 y1 = *(const float4*)(ki_g + gb + 4);
  float4 y2 = *(const float4*)(ki_g + gb + 8);
  float4 y3 = *(const float4*)(ki_g + gb + 12);
  *(bf16x8*)((char*)kb_i + tb + row * 128 + ((d0 * 2) ^ swz))      = pack8(y0, y1);
  *(bf16x8*)((char*)kb_i + tb + row * 128 + ((d0 * 2 + 16) ^ swz)) = pack8(y2, y3);
}

__global__ __launch_bounds__(256) void prep_v_kernel(
    const float* __restrict__ vr_g, const float* __restrict__ vi_g,
    __hip_bfloat16* __restrict__ vt_r, __hip_bfloat16* __restrict__ vt_i)
{
  __shared__ __align__(16) char lds_raw[2 * 8192];
  char* tr = lds_raw;
  char* ti = lds_raw + 8192;

  const int tid = threadIdx.x;
  const int bh  = blockIdx.x >> 5;
  const int kb  = blockIdx.x & 31;
  const int k0  = kb * 64;
  const size_t tb = ((size_t)bh * 32 + kb) * 8192;

  {
    const int row = tid >> 2;
    const int d0  = (tid & 3) << 4;
    const size_t gb = ((size_t)bh * kL + k0 + row) * kD + d0;
    const int swz = (row & 7) << 4;
    float4 x0 = *(const float4*)(vr_g + gb);
    float4 x1 = *(const float4*)(vr_g + gb + 4);
    float4 x2 = *(const float4*)(vr_g + gb + 8);
    float4 x3 = *(const float4*)(vr_g + gb + 12);
    *(bf16x8*)(tr + row * 128 + ((d0 * 2) ^ swz))      = pack8(x0, x1);
    *(bf16x8*)(tr + row * 128 + ((d0 * 2 + 16) ^ swz)) = pack8(x2, x3);
    float4 y0 = *(const float4*)(vi_g + gb);
    float4 y1 = *(const float4*)(vi_g + gb + 4);
    float4 y2 = *(const float4*)(vi_g + gb + 8);
    float4 y3 = *(const float4*)(vi_g + gb + 12);
    *(bf16x8*)(ti + row * 128 + ((d0 * 2) ^ swz))      = pack8(y0, y1);
    *(bf16x8*)(ti + row * 128 + ((d0 * 2 + 16) ^ swz)) = pack8(y2, y3);
  }
  __syncthreads();
  {
    const int d  = tid >> 2;
    const int kc = (tid & 3) << 4;
    char* outr = (char*)vt_r + tb + d * 128;
    char* outi = (char*)vt_i + tb + d * 128;
    const int oswz = (d & 7) << 4;
    bf16x8 pr0, pr1, pi0, pi1;
#pragma unroll
    for (int j = 0; j < 8; ++j) {
      const int k1 = kc + j;
      const int k2 = kc + 8 + j;
      const int b1 = k1 * 128 + ((d * 2) ^ ((k1 & 7) << 4));
      const int b2 = k2 * 128 + ((d * 2) ^ ((k2 & 7) << 4));
      pr0[j] = *(const __bf16*)(tr + b1);
      pr1[j] = *(const __bf16*)(tr + b2);
      pi0[j] = *(const __bf16*)(ti + b1);
      pi1[j] = *(const __bf16*)(ti + b2);
    }
    *(bf16x8*)(outr + ((kc * 2) ^ oswz))      = pr0;
    *(bf16x8*)(outr + ((kc * 2 + 16) ^ oswz)) = pr1;
    *(bf16x8*)(outi + ((kc * 2) ^ oswz))      = pi0;
    *(bf16x8*)(outi + ((kc * 2 + 16) ^ oswz)) = pi1;
  }
}

// ---------------------------------------------------------------------------
// Kernel A: e = exp(|<q/8, conj(k)>|) -> ews bf16 (coalesced); rowsums.
// (R12-proven: counted vmcnt(4), raw barrier, gl_lds double-buffer.)
// ---------------------------------------------------------------------------
__global__ __launch_bounds__(256) void qk_ews(
    const float* __restrict__ qr_g, const float* __restrict__ qi_g,
    const __hip_bfloat16* __restrict__ kb_r, const __hip_bfloat16* __restrict__ kb_i,
    __hip_bfloat16* __restrict__ ews, float* __restrict__ rowsum)
{
  __shared__ __align__(16) char lds_raw[49152];
  char* e_l = lds_raw + 32768 + (threadIdx.x >> 6) * 4096;

  const int tid  = threadIdx.x;
  const int wave = tid >> 6;
  const int lane = tid & 63;
  const int g    = lane >> 4;   // 0..3
  const int r    = lane & 15;   // 0..15

  const int bid = blockIdx.x;
  const int nid = (bid & 7) * 128 + (bid >> 3);   // XCD-bijective swizzle
  const int bh  = nid >> 4;
  const int q0w = (nid & 15) * 128 + wave * 32;

  bf16x8 aqr[2][2], aqi[2][2], aqrn[2][2];
#pragma unroll
  for (int qt = 0; qt < 2; ++qt) {
    const size_t qbase = ((size_t)bh * kL + q0w + qt * 16 + r) * kD + g * 8;
#pragma unroll
    for (int f = 0; f < 2; ++f) {
      float4 x0 = *(const float4*)(qr_g + qbase + f * 32);
      float4 x1 = *(const float4*)(qr_g + qbase + f * 32 + 4);
      float4 y0 = *(const float4*)(qi_g + qbase + f * 32);
      float4 y1 = *(const float4*)(qi_g + qbase + f * 32 + 4);
      float xr[8] = {x0.x, x0.y, x0.z, x0.w, x1.x, x1.y, x1.z, x1.w};
      float xi[8] = {y0.x, y0.y, y0.z, y0.w, y1.x, y1.y, y1.z, y1.w};
#pragma unroll
      for (int i = 0; i < 8; ++i) {
        aqr[qt][f][i] = (__bf16)(xr[i] * 0.125f);
        aqi[qt][f][i] = (__bf16)(xi[i] * 0.125f);
      }
      aqrn[qt][f] = neg8(aqr[qt][f]);
    }
  }

  float rs[2] = {0.f, 0.f};
  const int off1 = tid * 16;        // [0,4096)
  const int off2 = off1 + 4096;     // [4096,8192)
  const size_t tbase = (size_t)bh * 32 * 8192;

  auto ISSUE = [&](char* buf, int t) {
    const char* sr = (const char*)kb_r + tbase + (size_t)t * 8192;
    const char* si = (const char*)kb_i + tbase + (size_t)t * 8192;
    gl_lds16(buf + off1, sr + off1);
    gl_lds16(buf + off2, sr + off2);
    gl_lds16(buf + 8192 + off1, si + off1);
    gl_lds16(buf + 8192 + off2, si + off2);
  };

  ISSUE(lds_raw, 0);

#pragma unroll 1
  for (int t = 0; t < 32; ++t) {
    char* cbuf = lds_raw + (t & 1) * 16384;
    char* nbuf = lds_raw + ((t + 1) & 1) * 16384;
    if (t == 0) asm volatile("s_waitcnt vmcnt(0)" ::: "memory");
    else        asm volatile("s_waitcnt vmcnt(4)" ::: "memory");
    __builtin_amdgcn_s_barrier();
    __builtin_amdgcn_sched_barrier(0);
    if (t < 31) ISSUE(nbuf, t + 1);
    __builtin_amdgcn_sched_barrier(0);
    const int k0 = t * 64;

#pragma unroll
    for (int s = 0; s < 4; ++s) {
      const int krow = s * 16 + r;
      const int swz  = (krow & 7) << 4;
      bf16x8 bkr[2], bki[2];
#pragma unroll
      for (int f = 0; f < 2; ++f) {
        const int byte = krow * 128 + (((f * 32 + g * 8) * 2) ^ swz);
        bkr[f] = *(const bf16x8*)(cbuf + byte);
        bki[f] = *(const bf16x8*)(cbuf + 8192 + byte);
      }
#pragma unroll
      for (int qt = 0; qt < 2; ++qt) {
        f32x4 accr = {0.f, 0.f, 0.f, 0.f};
        f32x4 acci = {0.f, 0.f, 0.f, 0.f};
#pragma unroll
        for (int f = 0; f < 2; ++f) {
          accr = __builtin_amdgcn_mfma_f32_16x16x32_bf16(bkr[f], aqr[qt][f],  accr, 0, 0, 0);
          accr = __builtin_amdgcn_mfma_f32_16x16x32_bf16(bki[f], aqi[qt][f],  accr, 0, 0, 0);
          acci = __builtin_amdgcn_mfma_f32_16x16x32_bf16(bkr[f], aqi[qt][f],  acci, 0, 0, 0);
          acci = __builtin_amdgcn_mfma_f32_16x16x32_bf16(bki[f], aqrn[qt][f], acci, 0, 0, 0);
        }
        float e[4];
#pragma unroll
        for (int i = 0; i < 4; ++i)
          e[i] = __expf(sqrtf(accr[i] * accr[i] + acci[i] * acci[i]));
        rs[qt] += (e[0] + e[1]) + (e[2] + e[3]);
        bf16x4 pe;
#pragma unroll
        for (int i = 0; i < 4; ++i) pe[i] = (__bf16)e[i];
        const int row = qt * 16 + r;
        *(bf16x4*)(e_l + row * 128 + (((s * 16 + g * 4) * 2) ^ ((row & 7) << 4))) = pe;
      }
    }

#pragma unroll
    for (int m = 0; m < 4; ++m) {
      const int row  = m * 8 + (lane >> 3);
      const int byte = row * 128 + (((lane & 7) * 16) ^ ((row & 7) << 4));
      bf16x8 v = *(const bf16x8*)(e_l + byte);
      const size_t base = ((size_t)bh * kL + q0w + row) * kL + k0 + (lane & 7) * 8;
      *(bf16x8*)((__bf16*)ews + base) = v;
    }
  }

#pragma unroll
  for (int qt = 0; qt < 2; ++qt) {
    rs[qt] += __shfl_xor(rs[qt], 16, 64);
    rs[qt] += __shfl_xor(rs[qt], 32, 64);
  }
  if (lane < 16) {
#pragma unroll
    for (int qt = 0; qt < 2; ++qt)
      rowsum[(size_t)bh * kL + q0w + qt * 16 + lane] = rs[qt];
  }
}

// ---------------------------------------------------------------------------
// Kernel B: normalized attn (f32) + out = (e @ V) / rowsum.
// NEW: e-fragments prefetched one chunk ahead (named efA/efB, static index);
// sched_barrier pins keep the counted-vmcnt issue-order exact:
//   steady-state outstanding at barrier = [DMA x4, ef x4, stores x8]
//   -> vmcnt(12) waits only the DMA.
// ---------------------------------------------------------------------------
__global__ __launch_bounds__(256) void pv_norm(
    const __hip_bfloat16* __restrict__ vt_r, const __hip_bfloat16* __restrict__ vt_i,
    const __hip_bfloat16* __restrict__ ews, float* __restrict__ attn,
    const float* __restrict__ rowsum, float* __restrict__ out)
{
  __shared__ __align__(16) char lds_raw[32768];

  const int tid  = threadIdx.x;
  const int wave = tid >> 6;
  const int lane = tid & 63;
  const int g    = lane >> 4;
  const int r    = lane & 15;

  const int bid = blockIdx.x;
  const int nid = (bid & 7) * 128 + (bid >> 3);
  const int bh  = nid >> 4;
  const int q0w = (nid & 15) * 128 + wave * 32;

  float invA[2];
  size_t ebase[2];
#pragma unroll
  for (int qt = 0; qt < 2; ++qt) {
    invA[qt]  = 1.0f / rowsum[(size_t)bh * kL + q0w + qt * 16 + r];
    ebase[qt] = ((size_t)bh * kL + q0w + qt * 16 + r) * kL;
  }

  f32x4 o_r[2][4], o_i[2][4];
#pragma unroll
  for (int qt = 0; qt < 2; ++qt)
#pragma unroll
    for (int dt = 0; dt < 4; ++dt) {
      o_r[qt][dt] = (f32x4){0.f, 0.f, 0.f, 0.f};
      o_i[qt][dt] = (f32x4){0.f, 0.f, 0.f, 0.f};
    }

  const int off1 = tid * 16;
  const int off2 = off1 + 4096;
  const size_t tbase = (size_t)bh * 32 * 8192;
  char* buf0 = lds_raw;
  char* buf1 = lds_raw + 16384;

  auto ISSUE = [&](char* buf, int t) {
    const char* sr = (const char*)vt_r + tbase + (size_t)t * 8192;
    const char* si = (const char*)vt_i + tbase + (size_t)t * 8192;
    gl_lds16(buf + off1, sr + off1);
    gl_lds16(buf + off2, sr + off2);
    gl_lds16(buf + 8192 + off1, si + off1);
    gl_lds16(buf + 8192 + off2, si + off2);
  };

  bf16x8 efA[2][2], efB[2][2];   // [kh][qt] — named double buffers (rule #20)
  auto LOADE = [&](int t, bf16x8 (&ef)[2][2]) {
#pragma unroll
    for (int kh = 0; kh < 2; ++kh)
#pragma unroll
      for (int qt = 0; qt < 2; ++qt)
        ef[kh][qt] = *(const bf16x8*)((const __bf16*)ews + ebase[qt] + t * 64 + kh * 32 + g * 8);
  };

  auto CHUNK = [&](int t, bf16x8 (&ef)[2][2], const char* cbuf) {
    const int k0 = t * 64;
    // normalized attn write (8 stores)
#pragma unroll
    for (int kh = 0; kh < 2; ++kh)
#pragma unroll
      for (int qt = 0; qt < 2; ++qt) {
        const size_t eb = ebase[qt] + k0 + kh * 32 + g * 8;
        bf16x8 v = ef[kh][qt];
        float4 w0, w1;
        w0.x = (float)v[0] * invA[qt]; w0.y = (float)v[1] * invA[qt];
        w0.z = (float)v[2] * invA[qt]; w0.w = (float)v[3] * invA[qt];
        w1.x = (float)v[4] * invA[qt]; w1.y = (float)v[5] * invA[qt];
        w1.z = (float)v[6] * invA[qt]; w1.w = (float)v[7] * invA[qt];
        *(float4*)(attn + eb)     = w0;
        *(float4*)(attn + eb + 4) = w1;
      }
    // PV MFMA
#pragma unroll
    for (int kh = 0; kh < 2; ++kh)
#pragma unroll
      for (int dt = 0; dt < 4; ++dt) {
        const int d = dt * 16 + r;
        const int byte = d * 128 + (((kh * 32 + g * 8) * 2) ^ ((d & 7) << 4));
        bf16x8 bvr = *(const bf16x8*)(cbuf + byte);
        bf16x8 bvi = *(const bf16x8*)(cbuf + 8192 + byte);
#pragma unroll
        for (int qt = 0; qt < 2; ++qt) {
          o_r[qt][dt] = __builtin_amdgcn_mfma_f32_16x16x32_bf16(ef[kh][qt], bvr, o_r[qt][dt], 0, 0, 0);
          o_i[qt][dt] = __builtin_amdgcn_mfma_f32_16x16x32_bf16(ef[kh][qt], bvi, o_i[qt][dt], 0, 0, 0);
        }
      }
  };

  // Prologue: DMA(0) then ef(0) — DMA oldest.
  ISSUE(buf0, 0);
  __builtin_amdgcn_sched_barrier(0);
  LOADE(0, efA);

#pragma unroll 1
  for (int t = 0; t < 32; t += 2) {
    // ---- even chunk t (buf0, efA) ----
    if (t == 0) asm volatile("s_waitcnt vmcnt(4)" ::: "memory");   // DMA(0) done; ef(0) may fly
    else        asm volatile("s_waitcnt vmcnt(12)" ::: "memory");  // DMA(t) done
    __builtin_amdgcn_s_barrier();
    __builtin_amdgcn_sched_barrier(0);
    ISSUE(buf1, t + 1);
    __builtin_amdgcn_sched_barrier(0);
    LOADE(t + 1, efB);
    __builtin_amdgcn_sched_barrier(0);
    CHUNK(t, efA, buf0);

    // ---- odd chunk t+1 (buf1, efB) ----
    asm volatile("s_waitcnt vmcnt(12)" ::: "memory");              // DMA(t+1) done
    __builtin_amdgcn_s_barrier();
    __builtin_amdgcn_sched_barrier(0);
    if (t + 2 < 32) {
      ISSUE(buf0, t + 2);
      __builtin_amdgcn_sched_barrier(0);
      LOADE(t + 2, efA);
      __builtin_amdgcn_sched_barrier(0);
    }
    CHUNK(t + 1, efB, buf1);
  }

#pragma unroll
  for (int qt = 0; qt < 2; ++qt)
#pragma unroll
    for (int i = 0; i < 4; ++i) {
      const size_t q = q0w + qt * 16 + g * 4 + i;
      const float iv = 1.0f / rowsum[(size_t)bh * kL + q];
#pragma unroll
      for (int dt = 0; dt < 4; ++dt) {
        const int d = dt * 16 + r;
        float2 val;
        val.x = o_r[qt][dt][i] * iv;
        val.y = o_i[qt][dt][i] * iv;
        *(float2*)(out + (((size_t)bh * kL + q) * kD + d) * 2) = val;
      }
    }
}

// ---------------------------------------------------------------------------
// Legacy fallback (ws too small for any tile path): e as f32 in attn region.
// ---------------------------------------------------------------------------
__global__ __launch_bounds__(256) void qk_exp_legacy(
    const float* __restrict__ qr_g, const float* __restrict__ qi_g,
    const float* __restrict__ kr_g, const float* __restrict__ ki_g,
    float* __restrict__ attn, float* __restrict__ rowsum)
{
  __shared__ __align__(16) char lds_raw[16384 + 4 * 4096];
  char* kr_l = lds_raw;
  char* ki_l = lds_raw + 8192;
  char* e_l  = lds_raw + 16384 + (threadIdx.x >> 6) * 4096;

  const int tid  = threadIdx.x;
  const int wave = tid >> 6;
  const int lane = tid & 63;
  const int g    = lane >> 4;
  const int r    = lane & 15;

  const int bid = blockIdx.x;
  const int nid = (bid & 7) * 128 + (bid >> 3);
  const int bh  = nid >> 4;
  const int q0w = (nid & 15) * 128 + wave * 32;

  bf16x8 aqr[2][2], aqi[2][2];
#pragma unroll
  for (int qt = 0; qt < 2; ++qt) {
    const size_t qbase = ((size_t)bh * kL + q0w + qt * 16 + r) * kD + g * 8;
#pragma unroll
    for (int f = 0; f < 2; ++f) {
      float4 x0 = *(const float4*)(qr_g + qbase + f * 32);
      float4 x1 = *(const float4*)(qr_g + qbase + f * 32 + 4);
      float4 y0 = *(const float4*)(qi_g + qbase + f * 32);
      float4 y1 = *(const float4*)(qi_g + qbase + f * 32 + 4);
      float xr[8] = {x0.x, x0.y, x0.z, x0.w, x1.x, x1.y, x1.z, x1.w};
      float xi[8] = {y0.x, y0.y, y0.z, y0.w, y1.x, y1.y, y1.z, y1.w};
#pragma unroll
      for (int i = 0; i < 8; ++i) {
        aqr[qt][f][i] = (__bf16)(xr[i] * 0.125f);
        aqi[qt][f][i] = (__bf16)(xi[i] * 0.125f);
      }
    }
  }

  float rs[2] = {0.f, 0.f};

  for (int k0 = 0; k0 < kL; k0 += 64) {
    __syncthreads();
    {
      const int row = tid >> 2;
      const int d0  = (tid & 3) << 4;
      const size_t gb = ((size_t)bh * kL + k0 + row) * kD + d0;
      const int base = row * 128;
      const int swz  = (row & 7) << 4;
      {
        float4 x0 = *(const float4*)(kr_g + gb);
        float4 x1 = *(const float4*)(kr_g + gb + 4);
        float4 x2 = *(const float4*)(kr_g + gb + 8);
        float4 x3 = *(const float4*)(kr_g + gb + 12);
        *(bf16x8*)(kr_l + base + ((d0 * 2) ^ swz))      = pack8(x0, x1);
        *(bf16x8*)(kr_l + base + ((d0 * 2 + 16) ^ swz)) = pack8(x2, x3);
      }
      {
        float4 x0 = *(const float4*)(ki_g + gb);
        float4 x1 = *(const float4*)(ki_g + gb + 4);
        float4 x2 = *(const float4*)(ki_g + gb + 8);
        float4 x3 = *(const float4*)(ki_g + gb + 12);
        *(bf16x8*)(ki_l + base + ((d0 * 2) ^ swz))      = pack8(x0, x1);
        *(bf16x8*)(ki_l + base + ((d0 * 2 + 16) ^ swz)) = pack8(x2, x3);
      }
    }
    __syncthreads();

#pragma unroll
    for (int s = 0; s < 4; ++s) {
      const int krow = s * 16 + r;
      const int swz  = (krow & 7) << 4;
      bf16x8 bkr[2], bki[2], bkin[2];
#pragma unroll
      for (int f = 0; f < 2; ++f) {
        const int byte = krow * 128 + (((f * 32 + g * 8) * 2) ^ swz);
        bkr[f]  = *(const bf16x8*)(kr_l + byte);
        bki[f]  = *(const bf16x8*)(ki_l + byte);
        bkin[f] = neg8(bki[f]);
      }
#pragma unroll
      for (int qt = 0; qt < 2; ++qt) {
        f32x4 accr = {0.f, 0.f, 0.f, 0.f};
        f32x4 acci = {0.f, 0.f, 0.f, 0.f};
#pragma unroll
        for (int f = 0; f < 2; ++f) {
          accr = __builtin_amdgcn_mfma_f32_16x16x32_bf16(bkr[f],  aqr[qt][f], accr, 0, 0, 0);
          accr = __builtin_amdgcn_mfma_f32_16x16x32_bf16(bki[f],  aqi[qt][f], accr, 0, 0, 0);
          acci = __builtin_amdgcn_mfma_f32_16x16x32_bf16(bkr[f],  aqi[qt][f], acci, 0, 0, 0);
          acci = __builtin_amdgcn_mfma_f32_16x16x32_bf16(bkin[f], aqr[qt][f], acci, 0, 0, 0);
        }
        float e[4];
#pragma unroll
        for (int i = 0; i < 4; ++i)
          e[i] = __expf(sqrtf(accr[i] * accr[i] + acci[i] * acci[i]));
        rs[qt] += (e[0] + e[1]) + (e[2] + e[3]);
        bf16x4 pe;
#pragma unroll
        for (int i = 0; i < 4; ++i) pe[i] = (__bf16)e[i];
        const int row = qt * 16 + r;
        *(bf16x4*)(e_l + row * 128 + (((s * 16 + g * 4) * 2) ^ ((row & 7) << 4))) = pe;
      }
    }

#pragma unroll
    for (int m = 0; m < 4; ++m) {
      const int row  = m * 8 + (lane >> 3);
      const int byte = row * 128 + (((lane & 7) * 16) ^ ((row & 7) << 4));
      bf16x8 v = *(const bf16x8*)(e_l + byte);
      const size_t base = ((size_t)bh * kL + q0w + row) * kL + k0 + (lane & 7) * 8;
      float4 w0, w1;
      w0.x=(float)v[0]; w0.y=(float)v[1]; w0.z=(float)v[2]; w0.w=(float)v[3];
      w1.x=(float)v[4]; w1.y=(float)v[5]; w1.z=(float)v[6]; w1.w=(float)v[7];
      *(float4*)(attn + base)     = w0;
      *(float4*)(attn + base + 4) = w1;
    }
  }

#pragma unroll
  for (int qt = 0; qt < 2; ++qt) {
    rs[qt] += __shfl_xor(rs[qt], 16, 64);
    rs[qt] += __shfl_xor(rs[qt], 32, 64);
  }
  if (lane < 16) {
#pragma unroll
    for (int qt = 0; qt < 2; ++qt)
      rowsum[(size_t)bh * kL + q0w + qt * 16 + lane] = rs[qt];
  }
}

__global__ __launch_bounds__(256) void pv_legacy(
    const float* __restrict__ vr_g, const float* __restrict__ vi_g,
    float* __restrict__ attn, const float* __restrict__ rowsum,
    float* __restrict__ out)
{
  __shared__ __align__(16) char lds_raw[2 * 8192];
  char* vr_l = lds_raw;
  char* vi_l = lds_raw + 8192;

  const int tid  = threadIdx.x;
  const int wave = tid >> 6;
  const int lane = tid & 63;
  const int g    = lane >> 4;
  const int r    = lane & 15;

  const int bid = blockIdx.x;
  const int nid = (bid & 7) * 128 + (bid >> 3);
  const int bh  = nid >> 4;
  const int q0w = (nid & 15) * 128 + wave * 32;

  float invA[2];
#pragma unroll
  for (int qt = 0; qt < 2; ++qt)
    invA[qt] = 1.0f / rowsum[(size_t)bh * kL + q0w + qt * 16 + r];

  f32x4 o_r[2][4], o_i[2][4];
#pragma unroll
  for (int qt = 0; qt < 2; ++qt)
#pragma unroll
    for (int dt = 0; dt < 4; ++dt) {
      o_r[qt][dt] = (f32x4){0.f, 0.f, 0.f, 0.f};
      o_i[qt][dt] = (f32x4){0.f, 0.f, 0.f, 0.f};
    }

  for (int k0 = 0; k0 < kL; k0 += 64) {
    __syncthreads();
    {
      const int p  = tid >> 3;
      const int d0 = (tid & 7) << 3;
      const size_t gb0 = ((size_t)bh * kL + k0 + 2 * p) * kD + d0;
      const size_t gb1 = gb0 + kD;
      float4 a0 = *(const float4*)(vr_g + gb0);
      float4 a1 = *(const float4*)(vr_g + gb0 + 4);
      float4 a2 = *(const float4*)(vr_g + gb1);
      float4 a3 = *(const float4*)(vr_g + gb1 + 4);
      float4 b0 = *(const float4*)(vi_g + gb0);
      float4 b1 = *(const float4*)(vi_g + gb0 + 4);
      float4 b2 = *(const float4*)(vi_g + gb1);
      float4 b3 = *(const float4*)(vi_g + gb1 + 4);
      float vr0[8] = {a0.x, a0.y, a0.z, a0.w, a1.x, a1.y, a1.z, a1.w};
      float vr1[8] = {a2.x, a2.y, a2.z, a2.w, a3.x, a3.y, a3.z, a3.w};
      float vi0[8] = {b0.x, b0.y, b0.z, b0.w, b1.x, b1.y, b1.z, b1.w};
      float vi1[8] = {b2.x, b2.y, b2.z, b2.w, b3.x, b3.y, b3.z, b3.w};
#pragma unroll
      for (int j = 0; j < 8; ++j) {
        const int d = d0 + j;
        const int byte = d * 128 + ((p * 4) ^ ((d & 7) << 4));
        __bf16 pa[2] = {(__bf16)vr0[j], (__bf16)vr1[j]};
        __bf16 pb[2] = {(__bf16)vi0[j], (__bf16)vi1[j]};
        *(unsigned int*)(vr_l + byte) = *(unsigned int*)pa;
        *(unsigned int*)(vi_l + byte) = *(unsigned int*)pb;
      }
    }
    __syncthreads();

#pragma unroll
    for (int kh = 0; kh < 2; ++kh) {
      bf16x8 af[2];
#pragma unroll
      for (int qt = 0; qt < 2; ++qt) {
        const size_t q = q0w + qt * 16 + r;
        const size_t eb = ((size_t)bh * kL + q) * kL + k0 + kh * 32 + g * 8;
        float4 e0 = *(const float4*)(attn + eb);
        float4 e1 = *(const float4*)(attn + eb + 4);
        af[qt][0]=(__bf16)e0.x; af[qt][1]=(__bf16)e0.y; af[qt][2]=(__bf16)e0.z; af[qt][3]=(__bf16)e0.w;
        af[qt][4]=(__bf16)e1.x; af[qt][5]=(__bf16)e1.y; af[qt][6]=(__bf16)e1.z; af[qt][7]=(__bf16)e1.w;
        float4 w0 = {e0.x * invA[qt], e0.y * invA[qt], e0.z * invA[qt], e0.w * invA[qt]};
        float4 w1 = {e1.x * invA[qt], e1.y * invA[qt], e1.z * invA[qt], e1.w * invA[qt]};
        *(float4*)(attn + eb)     = w0;
        *(float4*)(attn + eb + 4) = w1;
      }
#pragma unroll
      for (int dt = 0; dt < 4; ++dt) {
        const int d = dt * 16 + r;
        const int byte = d * 128 + (((kh * 32 + g * 8) * 2) ^ ((d & 7) << 4));
        bf16x8 bvr = *(const bf16x8*)(vr_l + byte);
        bf16x8 bvi = *(const bf16x8*)(vi_l + byte);
#pragma unroll
        for (int qt = 0; qt < 2; ++qt) {
          o_r[qt][dt] = __builtin_amdgcn_mfma_f32_16x16x32_bf16(af[qt], bvr, o_r[qt][dt], 0, 0, 0);
          o_i[qt][dt] = __builtin_amdgcn_mfma_f32_16x16x32_bf16(af[qt], bvi, o_i[qt][dt], 0, 0, 0);
        }
      }
    }
  }

#pragma unroll
  for (int qt = 0; qt < 2; ++qt)
#pragma unroll
    for (int i = 0; i < 4; ++i) {
      const size_t q = q0w + qt * 16 + g * 4 + i;
      const float iv = 1.0f / rowsum[(size_t)bh * kL + q];
#pragma unroll
      for (int dt = 0; dt < 4; ++dt) {
        const int d = dt * 16 + r;
        float2 val;
        val.x = o_r[qt][dt][i] * iv;
        val.y = o_i[qt][dt][i] * iv;
        *(float2*)(out + (((size_t)bh * kL + q) * kD + d) * 2) = val;
      }
    }
}

extern "C" void kernel_launch(void* const* d_in, const int* in_sizes, int n_in,
                              void* d_out, int out_size, void* d_ws, size_t ws_size,
                              hipStream_t stream) {
  const float* qr = (const float*)d_in[0];
  const float* qi = (const float*)d_in[1];
  const float* kr = (const float*)d_in[2];
  const float* ki = (const float*)d_in[3];
  const float* vr = (const float*)d_in[4];
  const float* vi = (const float*)d_in[5];
  float* out  = (float*)d_out;
  float* attn = out + kAttnOff;

  const size_t rowsum_bytes = (size_t)kBH * kL * 4;              // 512 KB
  const size_t e_bytes      = (size_t)kBH * kL * kL * 2;         // 536.9 MB
  const size_t tile_bytes   = (size_t)kBH * kL * kD * 2;         // 16.78 MB each
  float* rowsum = (float*)d_ws;
  __hip_bfloat16* ews = (__hip_bfloat16*)((char*)d_ws + rowsum_bytes);
  char* tiles = (char*)d_ws + rowsum_bytes + e_bytes;
  __hip_bfloat16* t0 = (__hip_bfloat16*)(tiles);
  __hip_bfloat16* t1 = (__hip_bfloat16*)(tiles + tile_bytes);
  __hip_bfloat16* t2 = (__hip_bfloat16*)(tiles + 2 * tile_bytes);
  __hip_bfloat16* t3 = (__hip_bfloat16*)(tiles + 3 * tile_bytes);

  dim3 gridP(kBH * (kL / 64));    // 2048
  dim3 gridM(kBH * (kL / 128));   // 1024

  if (ws_size >= rowsum_bytes + e_bytes + 4 * tile_bytes) {
    // 604.6 MB: separate kb/vt buffers, single merged prep (3 launches).
    prep_all_kernel<<<gridP, 256, 0, stream>>>(kr, ki, vr, vi, t0, t1, t2, t3);
    qk_ews<<<gridM, 256, 0, stream>>>(qr, qi, t0, t1, ews, rowsum);
    pv_norm<<<gridM, 256, 0, stream>>>(t2, t3, ews, attn, rowsum, out);
  } else if (ws_size >= rowsum_bytes + e_bytes + 2 * tile_bytes) {
    // 571.0 MB: R12-proven time-shared tile buffer (4 launches).
    prep_k_kernel<<<gridP, 256, 0, stream>>>(kr, ki, t0, t1);
    qk_ews<<<gridM, 256, 0, stream>>>(qr, qi, t0, t1, ews, rowsum);
    prep_v_kernel<<<gridP, 256, 0, stream>>>(vr, vi, t0, t1);
    pv_norm<<<gridM, 256, 0, stream>>>(t0, t1, ews, attn, rowsum, out);
  } else {
    qk_exp_legacy<<<gridM, 256, 0, stream>>>(qr, qi, kr, ki, attn, rowsum);
    pv_legacy<<<gridM, 256, 0, stream>>>(vr, vi, attn, rowsum, out);
  }
}

// Round 14
// 676.119 us; speedup vs baseline: 1.0168x; 1.0168x over previous
//
#include <hip/hip_runtime.h>
#include <hip/hip_bf16.h>

// Problem constants
constexpr int kL  = 2048;   // sequence length
constexpr int kD  = 64;     // head dim
constexpr int kBH = 64;     // B*H = 4*16
constexpr size_t kAttnOff = (size_t)kBH * kL * kD * 2;  // output elems before attn

typedef __bf16 bf16x8 __attribute__((ext_vector_type(8)));
typedef __bf16 bf16x4 __attribute__((ext_vector_type(4)));
typedef float  f32x4  __attribute__((ext_vector_type(4)));
typedef unsigned int u32x4 __attribute__((ext_vector_type(4)));

static __device__ inline bf16x8 neg8(bf16x8 v) {
  u32x4 t = __builtin_bit_cast(u32x4, v);
  t ^= 0x80008000u;
  return __builtin_bit_cast(bf16x8, t);
}

static __device__ inline bf16x8 pack8(const float4& a, const float4& b) {
  bf16x8 p;
  p[0]=(__bf16)a.x; p[1]=(__bf16)a.y; p[2]=(__bf16)a.z; p[3]=(__bf16)a.w;
  p[4]=(__bf16)b.x; p[5]=(__bf16)b.y; p[6]=(__bf16)b.z; p[7]=(__bf16)b.w;
  return p;
}

// Async 16B global -> LDS (direct, no VGPR roundtrip). LDS dest is
// wave-uniform base + lane*16 (tid*16 pattern satisfies this).
static __device__ inline void gl_lds16(char* l, const char* g) {
  __builtin_amdgcn_global_load_lds(
      (const __attribute__((address_space(1))) void*)g,
      (__attribute__((address_space(3))) void*)l, 16, 0, 0);
}

// ---------------------------------------------------------------------------
// Merged prep kernel: kb tiles (K bf16, XOR-swizzled) + vt tiles (V^T bf16,
// swizzled). Tile (bh,kb)=8KB at (bh*32+kb)*8192.
//   kb: element (krow, d) at byte krow*128 + ((d*2) ^ ((krow&7)<<4))
//   vt: element (d, k)    at byte d*128    + ((k*2) ^ ((d&7)<<4))
// ---------------------------------------------------------------------------
__global__ __launch_bounds__(256) void prep_all_kernel(
    const float* __restrict__ kr_g, const float* __restrict__ ki_g,
    const float* __restrict__ vr_g, const float* __restrict__ vi_g,
    __hip_bfloat16* __restrict__ kb_r, __hip_bfloat16* __restrict__ kb_i,
    __hip_bfloat16* __restrict__ vt_r, __hip_bfloat16* __restrict__ vt_i)
{
  __shared__ __align__(16) char lds_raw[2 * 8192];
  char* tr = lds_raw;
  char* ti = lds_raw + 8192;

  const int tid = threadIdx.x;
  const int bh  = blockIdx.x >> 5;
  const int kb  = blockIdx.x & 31;
  const int k0  = kb * 64;
  const size_t tb = ((size_t)bh * 32 + kb) * 8192;

  const int row = tid >> 2;
  const int d0  = (tid & 3) << 4;
  const size_t gb = ((size_t)bh * kL + k0 + row) * kD + d0;
  const int swz = (row & 7) << 4;

  {
    float4 x0 = *(const float4*)(kr_g + gb);
    float4 x1 = *(const float4*)(kr_g + gb + 4);
    float4 x2 = *(const float4*)(kr_g + gb + 8);
    float4 x3 = *(const float4*)(kr_g + gb + 12);
    *(bf16x8*)((char*)kb_r + tb + row * 128 + ((d0 * 2) ^ swz))      = pack8(x0, x1);
    *(bf16x8*)((char*)kb_r + tb + row * 128 + ((d0 * 2 + 16) ^ swz)) = pack8(x2, x3);
    float4 y0 = *(const float4*)(ki_g + gb);
    float4 y1 = *(const float4*)(ki_g + gb + 4);
    float4 y2 = *(const float4*)(ki_g + gb + 8);
    float4 y3 = *(const float4*)(ki_g + gb + 12);
    *(bf16x8*)((char*)kb_i + tb + row * 128 + ((d0 * 2) ^ swz))      = pack8(y0, y1);
    *(bf16x8*)((char*)kb_i + tb + row * 128 + ((d0 * 2 + 16) ^ swz)) = pack8(y2, y3);
  }

  {
    float4 x0 = *(const float4*)(vr_g + gb);
    float4 x1 = *(const float4*)(vr_g + gb + 4);
    float4 x2 = *(const float4*)(vr_g + gb + 8);
    float4 x3 = *(const float4*)(vr_g + gb + 12);
    *(bf16x8*)(tr + row * 128 + ((d0 * 2) ^ swz))      = pack8(x0, x1);
    *(bf16x8*)(tr + row * 128 + ((d0 * 2 + 16) ^ swz)) = pack8(x2, x3);
    float4 y0 = *(const float4*)(vi_g + gb);
    float4 y1 = *(const float4*)(vi_g + gb + 4);
    float4 y2 = *(const float4*)(vi_g + gb + 8);
    float4 y3 = *(const float4*)(vi_g + gb + 12);
    *(bf16x8*)(ti + row * 128 + ((d0 * 2) ^ swz))      = pack8(y0, y1);
    *(bf16x8*)(ti + row * 128 + ((d0 * 2 + 16) ^ swz)) = pack8(y2, y3);
  }
  __syncthreads();
  {
    const int d  = tid >> 2;         // 0..63
    const int kc = (tid & 3) << 4;   // 0,16,32,48
    char* outr = (char*)vt_r + tb + d * 128;
    char* outi = (char*)vt_i + tb + d * 128;
    const int oswz = (d & 7) << 4;
    bf16x8 pr0, pr1, pi0, pi1;
#pragma unroll
    for (int j = 0; j < 8; ++j) {
      const int k1 = kc + j;
      const int k2 = kc + 8 + j;
      const int b1 = k1 * 128 + ((d * 2) ^ ((k1 & 7) << 4));
      const int b2 = k2 * 128 + ((d * 2) ^ ((k2 & 7) << 4));
      pr0[j] = *(const __bf16*)(tr + b1);
      pr1[j] = *(const __bf16*)(tr + b2);
      pi0[j] = *(const __bf16*)(ti + b1);
      pi1[j] = *(const __bf16*)(ti + b2);
    }
    *(bf16x8*)(outr + ((kc * 2) ^ oswz))      = pr0;
    *(bf16x8*)(outr + ((kc * 2 + 16) ^ oswz)) = pr1;
    *(bf16x8*)(outi + ((kc * 2) ^ oswz))      = pi0;
    *(bf16x8*)(outi + ((kc * 2 + 16) ^ oswz)) = pi1;
  }
}

// ---------------------------------------------------------------------------
// Prep-K / Prep-V kernels for the time-shared fallback path (R12-proven).
// ---------------------------------------------------------------------------
__global__ __launch_bounds__(256) void prep_k_kernel(
    const float* __restrict__ kr_g, const float* __restrict__ ki_g,
    __hip_bfloat16* __restrict__ kb_r, __hip_bfloat16* __restrict__ kb_i)
{
  const int tid = threadIdx.x;
  const int bh  = blockIdx.x >> 5;
  const int kb  = blockIdx.x & 31;
  const int k0  = kb * 64;
  const size_t tb = ((size_t)bh * 32 + kb) * 8192;

  const int row = tid >> 2;
  const int d0  = (tid & 3) << 4;
  const size_t gb = ((size_t)bh * kL + k0 + row) * kD + d0;
  const int swz = (row & 7) << 4;

  float4 x0 = *(const float4*)(kr_g + gb);
  float4 x1 = *(const float4*)(kr_g + gb + 4);
  float4 x2 = *(const float4*)(kr_g + gb + 8);
  float4 x3 = *(const float4*)(kr_g + gb + 12);
  *(bf16x8*)((char*)kb_r + tb + row * 128 + ((d0 * 2) ^ swz))      = pack8(x0, x1);
  *(bf16x8*)((char*)kb_r + tb + row * 128 + ((d0 * 2 + 16) ^ swz)) = pack8(x2, x3);
  float4 y0 = *(const float4*)(ki_g + gb);
  float4 y1 = *(const float4*)(ki_g + gb + 4);
  float4 y2 = *(const float4*)(ki_g + gb + 8);
  float4 y3 = *(const float4*)(ki_g + gb + 12);
  *(bf16x8*)((char*)kb_i + tb + row * 128 + ((d0 * 2) ^ swz))      = pack8(y0, y1);
  *(bf16x8*)((char*)kb_i + tb + row * 128 + ((d0 * 2 + 16) ^ swz)) = pack8(y2, y3);
}

__global__ __launch_bounds__(256) void prep_v_kernel(
    const float* __restrict__ vr_g, const float* __restrict__ vi_g,
    __hip_bfloat16* __restrict__ vt_r, __hip_bfloat16* __restrict__ vt_i)
{
  __shared__ __align__(16) char lds_raw[2 * 8192];
  char* tr = lds_raw;
  char* ti = lds_raw + 8192;

  const int tid = threadIdx.x;
  const int bh  = blockIdx.x >> 5;
  const int kb  = blockIdx.x & 31;
  const int k0  = kb * 64;
  const size_t tb = ((size_t)bh * 32 + kb) * 8192;

  {
    const int row = tid >> 2;
    const int d0  = (tid & 3) << 4;
    const size_t gb = ((size_t)bh * kL + k0 + row) * kD + d0;
    const int swz = (row & 7) << 4;
    float4 x0 = *(const float4*)(vr_g + gb);
    float4 x1 = *(const float4*)(vr_g + gb + 4);
    float4 x2 = *(const float4*)(vr_g + gb + 8);
    float4 x3 = *(const float4*)(vr_g + gb + 12);
    *(bf16x8*)(tr + row * 128 + ((d0 * 2) ^ swz))      = pack8(x0, x1);
    *(bf16x8*)(tr + row * 128 + ((d0 * 2 + 16) ^ swz)) = pack8(x2, x3);
    float4 y0 = *(const float4*)(vi_g + gb);
    float4 y1 = *(const float4*)(vi_g + gb + 4);
    float4 y2 = *(const float4*)(vi_g + gb + 8);
    float4 y3 = *(const float4*)(vi_g + gb + 12);
    *(bf16x8*)(ti + row * 128 + ((d0 * 2) ^ swz))      = pack8(y0, y1);
    *(bf16x8*)(ti + row * 128 + ((d0 * 2 + 16) ^ swz)) = pack8(y2, y3);
  }
  __syncthreads();
  {
    const int d  = tid >> 2;
    const int kc = (tid & 3) << 4;
    char* outr = (char*)vt_r + tb + d * 128;
    char* outi = (char*)vt_i + tb + d * 128;
    const int oswz = (d & 7) << 4;
    bf16x8 pr0, pr1, pi0, pi1;
#pragma unroll
    for (int j = 0; j < 8; ++j) {
      const int k1 = kc + j;
      const int k2 = kc + 8 + j;
      const int b1 = k1 * 128 + ((d * 2) ^ ((k1 & 7) << 4));
      const int b2 = k2 * 128 + ((d * 2) ^ ((k2 & 7) << 4));
      pr0[j] = *(const __bf16*)(tr + b1);
      pr1[j] = *(const __bf16*)(tr + b2);
      pi0[j] = *(const __bf16*)(ti + b1);
      pi1[j] = *(const __bf16*)(ti + b2);
    }
    *(bf16x8*)(outr + ((kc * 2) ^ oswz))      = pr0;
    *(bf16x8*)(outr + ((kc * 2 + 16) ^ oswz)) = pr1;
    *(bf16x8*)(outi + ((kc * 2) ^ oswz))      = pi0;
    *(bf16x8*)(outi + ((kc * 2 + 16) ^ oswz)) = pi1;
  }
}

// ---------------------------------------------------------------------------
// Kernel A: e = exp(|<q/8, conj(k)>|) -> ews bf16 (coalesced); rowsums.
// NEW (R14): LDS cut 48KB -> 40KB (per-wave e-tile 4KB -> 2KB, qt-outer
// compute+gather) => 4 blocks/CU instead of 3; __launch_bounds__(256,4).
// Counted vmcnt(4) + raw barrier (R12-proven): 4 DMA oldest, 4 stores fly.
// LDS 40KB: [0,16K) buf0 (kr,ki), [16K,32K) buf1, [32K,40K) per-wave e tiles.
// ---------------------------------------------------------------------------
__global__ __launch_bounds__(256, 4) void qk_ews(
    const float* __restrict__ qr_g, const float* __restrict__ qi_g,
    const __hip_bfloat16* __restrict__ kb_r, const __hip_bfloat16* __restrict__ kb_i,
    __hip_bfloat16* __restrict__ ews, float* __restrict__ rowsum)
{
  __shared__ __align__(16) char lds_raw[40960];
  char* e_l = lds_raw + 32768 + (threadIdx.x >> 6) * 2048;

  const int tid  = threadIdx.x;
  const int wave = tid >> 6;
  const int lane = tid & 63;
  const int g    = lane >> 4;   // 0..3
  const int r    = lane & 15;   // 0..15

  const int bid = blockIdx.x;
  const int nid = (bid & 7) * 128 + (bid >> 3);   // XCD-bijective swizzle
  const int bh  = nid >> 4;
  const int q0w = (nid & 15) * 128 + wave * 32;

  bf16x8 aqr[2][2], aqi[2][2], aqrn[2][2];
#pragma unroll
  for (int qt = 0; qt < 2; ++qt) {
    const size_t qbase = ((size_t)bh * kL + q0w + qt * 16 + r) * kD + g * 8;
#pragma unroll
    for (int f = 0; f < 2; ++f) {
      float4 x0 = *(const float4*)(qr_g + qbase + f * 32);
      float4 x1 = *(const float4*)(qr_g + qbase + f * 32 + 4);
      float4 y0 = *(const float4*)(qi_g + qbase + f * 32);
      float4 y1 = *(const float4*)(qi_g + qbase + f * 32 + 4);
      float xr[8] = {x0.x, x0.y, x0.z, x0.w, x1.x, x1.y, x1.z, x1.w};
      float xi[8] = {y0.x, y0.y, y0.z, y0.w, y1.x, y1.y, y1.z, y1.w};
#pragma unroll
      for (int i = 0; i < 8; ++i) {
        aqr[qt][f][i] = (__bf16)(xr[i] * 0.125f);
        aqi[qt][f][i] = (__bf16)(xi[i] * 0.125f);
      }
      aqrn[qt][f] = neg8(aqr[qt][f]);
    }
  }

  float rs[2] = {0.f, 0.f};
  const int off1 = tid * 16;        // [0,4096)
  const int off2 = off1 + 4096;     // [4096,8192)
  const size_t tbase = (size_t)bh * 32 * 8192;

  auto ISSUE = [&](char* buf, int t) {
    const char* sr = (const char*)kb_r + tbase + (size_t)t * 8192;
    const char* si = (const char*)kb_i + tbase + (size_t)t * 8192;
    gl_lds16(buf + off1, sr + off1);
    gl_lds16(buf + off2, sr + off2);
    gl_lds16(buf + 8192 + off1, si + off1);
    gl_lds16(buf + 8192 + off2, si + off2);
  };

  ISSUE(lds_raw, 0);

#pragma unroll 1
  for (int t = 0; t < 32; ++t) {
    char* cbuf = lds_raw + (t & 1) * 16384;
    char* nbuf = lds_raw + ((t + 1) & 1) * 16384;
    if (t == 0) asm volatile("s_waitcnt vmcnt(0)" ::: "memory");
    else        asm volatile("s_waitcnt vmcnt(4)" ::: "memory");
    __builtin_amdgcn_s_barrier();
    __builtin_amdgcn_sched_barrier(0);
    if (t < 31) ISSUE(nbuf, t + 1);
    __builtin_amdgcn_sched_barrier(0);
    const int k0 = t * 64;

#pragma unroll
    for (int qt = 0; qt < 2; ++qt) {
      // ---- compute qt's 16-row e tile ----
#pragma unroll
      for (int s = 0; s < 4; ++s) {
        const int krow = s * 16 + r;
        const int swz  = (krow & 7) << 4;
        bf16x8 bkr[2], bki[2];
#pragma unroll
        for (int f = 0; f < 2; ++f) {
          const int byte = krow * 128 + (((f * 32 + g * 8) * 2) ^ swz);
          bkr[f] = *(const bf16x8*)(cbuf + byte);
          bki[f] = *(const bf16x8*)(cbuf + 8192 + byte);
        }
        f32x4 accr = {0.f, 0.f, 0.f, 0.f};
        f32x4 acci = {0.f, 0.f, 0.f, 0.f};
#pragma unroll
        for (int f = 0; f < 2; ++f) {
          accr = __builtin_amdgcn_mfma_f32_16x16x32_bf16(bkr[f], aqr[qt][f],  accr, 0, 0, 0);
          accr = __builtin_amdgcn_mfma_f32_16x16x32_bf16(bki[f], aqi[qt][f],  accr, 0, 0, 0);
          acci = __builtin_amdgcn_mfma_f32_16x16x32_bf16(bkr[f], aqi[qt][f],  acci, 0, 0, 0);
          acci = __builtin_amdgcn_mfma_f32_16x16x32_bf16(bki[f], aqrn[qt][f], acci, 0, 0, 0);
        }
        float e[4];
#pragma unroll
        for (int i = 0; i < 4; ++i)
          e[i] = __expf(sqrtf(accr[i] * accr[i] + acci[i] * acci[i]));
        rs[qt] += (e[0] + e[1]) + (e[2] + e[3]);
        bf16x4 pe;
#pragma unroll
        for (int i = 0; i < 4; ++i) pe[i] = (__bf16)e[i];
        // e_l row = r (16 rows x 128B), col byte = (s*16+g*4)*2, XOR-swizzled
        *(bf16x4*)(e_l + r * 128 + (((s * 16 + g * 4) * 2) ^ ((r & 7) << 4))) = pe;
      }
      // ---- gather 16 rows -> coalesced 128B-per-row ews stores ----
      {
        const int row  = lane >> 2;          // 0..15
        const int cb   = (lane & 3) * 32;    // 0,32,64,96
        const int swzr = (row & 7) << 4;
        bf16x8 v0 = *(const bf16x8*)(e_l + row * 128 + (cb ^ swzr));
        bf16x8 v1 = *(const bf16x8*)(e_l + row * 128 + ((cb + 16) ^ swzr));
        const size_t base = ((size_t)bh * kL + q0w + qt * 16 + row) * kL + k0 + (lane & 3) * 16;
        *(bf16x8*)((__bf16*)ews + base)     = v0;
        *(bf16x8*)((__bf16*)ews + base + 8) = v1;
      }
    }
  }

#pragma unroll
  for (int qt = 0; qt < 2; ++qt) {
    rs[qt] += __shfl_xor(rs[qt], 16, 64);
    rs[qt] += __shfl_xor(rs[qt], 32, 64);
  }
  if (lane < 16) {
#pragma unroll
    for (int qt = 0; qt < 2; ++qt)
      rowsum[(size_t)bh * kL + q0w + qt * 16 + lane] = rs[qt];
  }
}

// ---------------------------------------------------------------------------
// Kernel B: normalized attn (f32) + out = (e @ V) / rowsum. (R12-proven.)
// V^T staged via double-buffered global_load_lds; counted vmcnt(8) before a
// raw barrier lets the 8 attn-stores stay in flight across chunks.
// LDS 32KB: [0,16K) buf0 (vr,vi), [16K,32K) buf1.
// ---------------------------------------------------------------------------
__global__ __launch_bounds__(256) void pv_norm(
    const __hip_bfloat16* __restrict__ vt_r, const __hip_bfloat16* __restrict__ vt_i,
    const __hip_bfloat16* __restrict__ ews, float* __restrict__ attn,
    const float* __restrict__ rowsum, float* __restrict__ out)
{
  __shared__ __align__(16) char lds_raw[32768];

  const int tid  = threadIdx.x;
  const int wave = tid >> 6;
  const int lane = tid & 63;
  const int g    = lane >> 4;
  const int r    = lane & 15;

  const int bid = blockIdx.x;
  const int nid = (bid & 7) * 128 + (bid >> 3);
  const int bh  = nid >> 4;
  const int q0w = (nid & 15) * 128 + wave * 32;

  float invA[2];
  size_t ebase[2];
#pragma unroll
  for (int qt = 0; qt < 2; ++qt) {
    invA[qt]  = 1.0f / rowsum[(size_t)bh * kL + q0w + qt * 16 + r];
    ebase[qt] = ((size_t)bh * kL + q0w + qt * 16 + r) * kL;
  }

  f32x4 o_r[2][4], o_i[2][4];
#pragma unroll
  for (int qt = 0; qt < 2; ++qt)
#pragma unroll
    for (int dt = 0; dt < 4; ++dt) {
      o_r[qt][dt] = (f32x4){0.f, 0.f, 0.f, 0.f};
      o_i[qt][dt] = (f32x4){0.f, 0.f, 0.f, 0.f};
    }

  const int off1 = tid * 16;
  const int off2 = off1 + 4096;
  const size_t tbase = (size_t)bh * 32 * 8192;

  auto ISSUE = [&](char* buf, int t) {
    const char* sr = (const char*)vt_r + tbase + (size_t)t * 8192;
    const char* si = (const char*)vt_i + tbase + (size_t)t * 8192;
    gl_lds16(buf + off1, sr + off1);
    gl_lds16(buf + off2, sr + off2);
    gl_lds16(buf + 8192 + off1, si + off1);
    gl_lds16(buf + 8192 + off2, si + off2);
  };

  ISSUE(lds_raw, 0);

#pragma unroll 1
  for (int t = 0; t < 32; ++t) {
    char* cbuf = lds_raw + (t & 1) * 16384;
    char* nbuf = lds_raw + ((t + 1) & 1) * 16384;
    if (t == 0) asm volatile("s_waitcnt vmcnt(0)" ::: "memory");
    else        asm volatile("s_waitcnt vmcnt(8)" ::: "memory");
    __builtin_amdgcn_s_barrier();
    __builtin_amdgcn_sched_barrier(0);
    if (t < 31) ISSUE(nbuf, t + 1);
    const int k0 = t * 64;

    bf16x8 ef[2][2];   // [kh][qt]
#pragma unroll
    for (int kh = 0; kh < 2; ++kh)
#pragma unroll
      for (int qt = 0; qt < 2; ++qt) {
        const size_t eb = ebase[qt] + k0 + kh * 32 + g * 8;
        bf16x8 v = *(const bf16x8*)((const __bf16*)ews + eb);
        ef[kh][qt] = v;
        float4 w0, w1;
        w0.x = (float)v[0] * invA[qt]; w0.y = (float)v[1] * invA[qt];
        w0.z = (float)v[2] * invA[qt]; w0.w = (float)v[3] * invA[qt];
        w1.x = (float)v[4] * invA[qt]; w1.y = (float)v[5] * invA[qt];
        w1.z = (float)v[6] * invA[qt]; w1.w = (float)v[7] * invA[qt];
        *(float4*)(attn + eb)     = w0;
        *(float4*)(attn + eb + 4) = w1;
      }

#pragma unroll
    for (int kh = 0; kh < 2; ++kh)
#pragma unroll
      for (int dt = 0; dt < 4; ++dt) {
        const int d = dt * 16 + r;
        const int byte = d * 128 + (((kh * 32 + g * 8) * 2) ^ ((d & 7) << 4));
        bf16x8 bvr = *(const bf16x8*)(cbuf + byte);
        bf16x8 bvi = *(const bf16x8*)(cbuf + 8192 + byte);
#pragma unroll
        for (int qt = 0; qt < 2; ++qt) {
          o_r[qt][dt] = __builtin_amdgcn_mfma_f32_16x16x32_bf16(ef[kh][qt], bvr, o_r[qt][dt], 0, 0, 0);
          o_i[qt][dt] = __builtin_amdgcn_mfma_f32_16x16x32_bf16(ef[kh][qt], bvi, o_i[qt][dt], 0, 0, 0);
        }
      }
  }

#pragma unroll
  for (int qt = 0; qt < 2; ++qt)
#pragma unroll
    for (int i = 0; i < 4; ++i) {
      const size_t q = q0w + qt * 16 + g * 4 + i;
      const float iv = 1.0f / rowsum[(size_t)bh * kL + q];
#pragma unroll
      for (int dt = 0; dt < 4; ++dt) {
        const int d = dt * 16 + r;
        float2 val;
        val.x = o_r[qt][dt][i] * iv;
        val.y = o_i[qt][dt][i] * iv;
        *(float2*)(out + (((size_t)bh * kL + q) * kD + d) * 2) = val;
      }
    }
}

// ---------------------------------------------------------------------------
// Legacy fallback (ws too small for any tile path): e as f32 in attn region.
// ---------------------------------------------------------------------------
__global__ __launch_bounds__(256) void qk_exp_legacy(
    const float* __restrict__ qr_g, const float* __restrict__ qi_g,
    const float* __restrict__ kr_g, const float* __restrict__ ki_g,
    float* __restrict__ attn, float* __restrict__ rowsum)
{
  __shared__ __align__(16) char lds_raw[16384 + 4 * 4096];
  char* kr_l = lds_raw;
  char* ki_l = lds_raw + 8192;
  char* e_l  = lds_raw + 16384 + (threadIdx.x >> 6) * 4096;

  const int tid  = threadIdx.x;
  const int wave = tid >> 6;
  const int lane = tid & 63;
  const int g    = lane >> 4;
  const int r    = lane & 15;

  const int bid = blockIdx.x;
  const int nid = (bid & 7) * 128 + (bid >> 3);
  const int bh  = nid >> 4;
  const int q0w = (nid & 15) * 128 + wave * 32;

  bf16x8 aqr[2][2], aqi[2][2];
#pragma unroll
  for (int qt = 0; qt < 2; ++qt) {
    const size_t qbase = ((size_t)bh * kL + q0w + qt * 16 + r) * kD + g * 8;
#pragma unroll
    for (int f = 0; f < 2; ++f) {
      float4 x0 = *(const float4*)(qr_g + qbase + f * 32);
      float4 x1 = *(const float4*)(qr_g + qbase + f * 32 + 4);
      float4 y0 = *(const float4*)(qi_g + qbase + f * 32);
      float4 y1 = *(const float4*)(qi_g + qbase + f * 32 + 4);
      float xr[8] = {x0.x, x0.y, x0.z, x0.w, x1.x, x1.y, x1.z, x1.w};
      float xi[8] = {y0.x, y0.y, y0.z, y0.w, y1.x, y1.y, y1.z, y1.w};
#pragma unroll
      for (int i = 0; i < 8; ++i) {
        aqr[qt][f][i] = (__bf16)(xr[i] * 0.125f);
        aqi[qt][f][i] = (__bf16)(xi[i] * 0.125f);
      }
    }
  }

  float rs[2] = {0.f, 0.f};

  for (int k0 = 0; k0 < kL; k0 += 64) {
    __syncthreads();
    {
      const int row = tid >> 2;
      const int d0  = (tid & 3) << 4;
      const size_t gb = ((size_t)bh * kL + k0 + row) * kD + d0;
      const int base = row * 128;
      const int swz  = (row & 7) << 4;
      {
        float4 x0 = *(const float4*)(kr_g + gb);
        float4 x1 = *(const float4*)(kr_g + gb + 4);
        float4 x2 = *(const float4*)(kr_g + gb + 8);
        float4 x3 = *(const float4*)(kr_g + gb + 12);
        *(bf16x8*)(kr_l + base + ((d0 * 2) ^ swz))      = pack8(x0, x1);
        *(bf16x8*)(kr_l + base + ((d0 * 2 + 16) ^ swz)) = pack8(x2, x3);
      }
      {
        float4 x0 = *(const float4*)(ki_g + gb);
        float4 x1 = *(const float4*)(ki_g + gb + 4);
        float4 x2 = *(const float4*)(ki_g + gb + 8);
        float4 x3 = *(const float4*)(ki_g + gb + 12);
        *(bf16x8*)(ki_l + base + ((d0 * 2) ^ swz))      = pack8(x0, x1);
        *(bf16x8*)(ki_l + base + ((d0 * 2 + 16) ^ swz)) = pack8(x2, x3);
      }
    }
    __syncthreads();

#pragma unroll
    for (int s = 0; s < 4; ++s) {
      const int krow = s * 16 + r;
      const int swz  = (krow & 7) << 4;
      bf16x8 bkr[2], bki[2], bkin[2];
#pragma unroll
      for (int f = 0; f < 2; ++f) {
        const int byte = krow * 128 + (((f * 32 + g * 8) * 2) ^ swz);
        bkr[f]  = *(const bf16x8*)(kr_l + byte);
        bki[f]  = *(const bf16x8*)(ki_l + byte);
        bkin[f] = neg8(bki[f]);
      }
#pragma unroll
      for (int qt = 0; qt < 2; ++qt) {
        f32x4 accr = {0.f, 0.f, 0.f, 0.f};
        f32x4 acci = {0.f, 0.f, 0.f, 0.f};
#pragma unroll
        for (int f = 0; f < 2; ++f) {
          accr = __builtin_amdgcn_mfma_f32_16x16x32_bf16(bkr[f],  aqr[qt][f], accr, 0, 0, 0);
          accr = __builtin_amdgcn_mfma_f32_16x16x32_bf16(bki[f],  aqi[qt][f], accr, 0, 0, 0);
          acci = __builtin_amdgcn_mfma_f32_16x16x32_bf16(bkr[f],  aqi[qt][f], acci, 0, 0, 0);
          acci = __builtin_amdgcn_mfma_f32_16x16x32_bf16(bkin[f], aqr[qt][f], acci, 0, 0, 0);
        }
        float e[4];
#pragma unroll
        for (int i = 0; i < 4; ++i)
          e[i] = __expf(sqrtf(accr[i] * accr[i] + acci[i] * acci[i]));
        rs[qt] += (e[0] + e[1]) + (e[2] + e[3]);
        bf16x4 pe;
#pragma unroll
        for (int i = 0; i < 4; ++i) pe[i] = (__bf16)e[i];
        const int row = qt * 16 + r;
        *(bf16x4*)(e_l + row * 128 + (((s * 16 + g * 4) * 2) ^ ((row & 7) << 4))) = pe;
      }
    }

#pragma unroll
    for (int m = 0; m < 4; ++m) {
      const int row  = m * 8 + (lane >> 3);
      const int byte = row * 128 + (((lane & 7) * 16) ^ ((row & 7) << 4));
      bf16x8 v = *(const bf16x8*)(e_l + byte);
      const size_t base = ((size_t)bh * kL + q0w + row) * kL + k0 + (lane & 7) * 8;
      float4 w0, w1;
      w0.x=(float)v[0]; w0.y=(float)v[1]; w0.z=(float)v[2]; w0.w=(float)v[3];
      w1.x=(float)v[4]; w1.y=(float)v[5]; w1.z=(float)v[6]; w1.w=(float)v[7];
      *(float4*)(attn + base)     = w0;
      *(float4*)(attn + base + 4) = w1;
    }
  }

#pragma unroll
  for (int qt = 0; qt < 2; ++qt) {
    rs[qt] += __shfl_xor(rs[qt], 16, 64);
    rs[qt] += __shfl_xor(rs[qt], 32, 64);
  }
  if (lane < 16) {
#pragma unroll
    for (int qt = 0; qt < 2; ++qt)
      rowsum[(size_t)bh * kL + q0w + qt * 16 + lane] = rs[qt];
  }
}

__global__ __launch_bounds__(256) void pv_legacy(
    const float* __restrict__ vr_g, const float* __restrict__ vi_g,
    float* __restrict__ attn, const float* __restrict__ rowsum,
    float* __restrict__ out)
{
  __shared__ __align__(16) char lds_raw[2 * 8192];
  char* vr_l = lds_raw;
  char* vi_l = lds_raw + 8192;

  const int tid  = threadIdx.x;
  const int wave = tid >> 6;
  const int lane = tid & 63;
  const int g    = lane >> 4;
  const int r    = lane & 15;

  const int bid = blockIdx.x;
  const int nid = (bid & 7) * 128 + (bid >> 3);
  const int bh  = nid >> 4;
  const int q0w = (nid & 15) * 128 + wave * 32;

  float invA[2];
#pragma unroll
  for (int qt = 0; qt < 2; ++qt)
    invA[qt] = 1.0f / rowsum[(size_t)bh * kL + q0w + qt * 16 + r];

  f32x4 o_r[2][4], o_i[2][4];
#pragma unroll
  for (int qt = 0; qt < 2; ++qt)
#pragma unroll
    for (int dt = 0; dt < 4; ++dt) {
      o_r[qt][dt] = (f32x4){0.f, 0.f, 0.f, 0.f};
      o_i[qt][dt] = (f32x4){0.f, 0.f, 0.f, 0.f};
    }

  for (int k0 = 0; k0 < kL; k0 += 64) {
    __syncthreads();
    {
      const int p  = tid >> 3;
      const int d0 = (tid & 7) << 3;
      const size_t gb0 = ((size_t)bh * kL + k0 + 2 * p) * kD + d0;
      const size_t gb1 = gb0 + kD;
      float4 a0 = *(const float4*)(vr_g + gb0);
      float4 a1 = *(const float4*)(vr_g + gb0 + 4);
      float4 a2 = *(const float4*)(vr_g + gb1);
      float4 a3 = *(const float4*)(vr_g + gb1 + 4);
      float4 b0 = *(const float4*)(vi_g + gb0);
      float4 b1 = *(const float4*)(vi_g + gb0 + 4);
      float4 b2 = *(const float4*)(vi_g + gb1);
      float4 b3 = *(const float4*)(vi_g + gb1 + 4);
      float vr0[8] = {a0.x, a0.y, a0.z, a0.w, a1.x, a1.y, a1.z, a1.w};
      float vr1[8] = {a2.x, a2.y, a2.z, a2.w, a3.x, a3.y, a3.z, a3.w};
      float vi0[8] = {b0.x, b0.y, b0.z, b0.w, b1.x, b1.y, b1.z, b1.w};
      float vi1[8] = {b2.x, b2.y, b2.z, b2.w, b3.x, b3.y, b3.z, b3.w};
#pragma unroll
      for (int j = 0; j < 8; ++j) {
        const int d = d0 + j;
        const int byte = d * 128 + ((p * 4) ^ ((d & 7) << 4));
        __bf16 pa[2] = {(__bf16)vr0[j], (__bf16)vr1[j]};
        __bf16 pb[2] = {(__bf16)vi0[j], (__bf16)vi1[j]};
        *(unsigned int*)(vr_l + byte) = *(unsigned int*)pa;
        *(unsigned int*)(vi_l + byte) = *(unsigned int*)pb;
      }
    }
    __syncthreads();

#pragma unroll
    for (int kh = 0; kh < 2; ++kh) {
      bf16x8 af[2];
#pragma unroll
      for (int qt = 0; qt < 2; ++qt) {
        const size_t q = q0w + qt * 16 + r;
        const size_t eb = ((size_t)bh * kL + q) * kL + k0 + kh * 32 + g * 8;
        float4 e0 = *(const float4*)(attn + eb);
        float4 e1 = *(const float4*)(attn + eb + 4);
        af[qt][0]=(__bf16)e0.x; af[qt][1]=(__bf16)e0.y; af[qt][2]=(__bf16)e0.z; af[qt][3]=(__bf16)e0.w;
        af[qt][4]=(__bf16)e1.x; af[qt][5]=(__bf16)e1.y; af[qt][6]=(__bf16)e1.z; af[qt][7]=(__bf16)e1.w;
        float4 w0 = {e0.x * invA[qt], e0.y * invA[qt], e0.z * invA[qt], e0.w * invA[qt]};
        float4 w1 = {e1.x * invA[qt], e1.y * invA[qt], e1.z * invA[qt], e1.w * invA[qt]};
        *(float4*)(attn + eb)     = w0;
        *(float4*)(attn + eb + 4) = w1;
      }
#pragma unroll
      for (int dt = 0; dt < 4; ++dt) {
        const int d = dt * 16 + r;
        const int byte = d * 128 + (((kh * 32 + g * 8) * 2) ^ ((d & 7) << 4));
        bf16x8 bvr = *(const bf16x8*)(vr_l + byte);
        bf16x8 bvi = *(const bf16x8*)(vi_l + byte);
#pragma unroll
        for (int qt = 0; qt < 2; ++qt) {
          o_r[qt][dt] = __builtin_amdgcn_mfma_f32_16x16x32_bf16(af[qt], bvr, o_r[qt][dt], 0, 0, 0);
          o_i[qt][dt] = __builtin_amdgcn_mfma_f32_16x16x32_bf16(af[qt], bvi, o_i[qt][dt], 0, 0, 0);
        }
      }
    }
  }

#pragma unroll
  for (int qt = 0; qt < 2; ++qt)
#pragma unroll
    for (int i = 0; i < 4; ++i) {
      const size_t q = q0w + qt * 16 + g * 4 + i;
      const float iv = 1.0f / rowsum[(size_t)bh * kL + q];
#pragma unroll
      for (int dt = 0; dt < 4; ++dt) {
        const int d = dt * 16 + r;
        float2 val;
        val.x = o_r[qt][dt][i] * iv;
        val.y = o_i[qt][dt][i] * iv;
        *(float2*)(out + (((size_t)bh * kL + q) * kD + d) * 2) = val;
      }
    }
}

extern "C" void kernel_launch(void* const* d_in, const int* in_sizes, int n_in,
                              void* d_out, int out_size, void* d_ws, size_t ws_size,
                              hipStream_t stream) {
  const float* qr = (const float*)d_in[0];
  const float* qi = (const float*)d_in[1];
  const float* kr = (const float*)d_in[2];
  const float* ki = (const float*)d_in[3];
  const float* vr = (const float*)d_in[4];
  const float* vi = (const float*)d_in[5];
  float* out  = (float*)d_out;
  float* attn = out + kAttnOff;

  const size_t rowsum_bytes = (size_t)kBH * kL * 4;              // 512 KB
  const size_t e_bytes      = (size_t)kBH * kL * kL * 2;         // 536.9 MB
  const size_t tile_bytes   = (size_t)kBH * kL * kD * 2;         // 16.78 MB each
  float* rowsum = (float*)d_ws;
  __hip_bfloat16* ews = (__hip_bfloat16*)((char*)d_ws + rowsum_bytes);
  char* tiles = (char*)d_ws + rowsum_bytes + e_bytes;
  __hip_bfloat16* t0 = (__hip_bfloat16*)(tiles);
  __hip_bfloat16* t1 = (__hip_bfloat16*)(tiles + tile_bytes);
  __hip_bfloat16* t2 = (__hip_bfloat16*)(tiles + 2 * tile_bytes);
  __hip_bfloat16* t3 = (__hip_bfloat16*)(tiles + 3 * tile_bytes);

  dim3 gridP(kBH * (kL / 64));    // 2048
  dim3 gridM(kBH * (kL / 128));   // 1024

  if (ws_size >= rowsum_bytes + e_bytes + 4 * tile_bytes) {
    // 604.6 MB: separate kb/vt buffers, single merged prep.
    prep_all_kernel<<<gridP, 256, 0, stream>>>(kr, ki, vr, vi, t0, t1, t2, t3);
    qk_ews<<<gridM, 256, 0, stream>>>(qr, qi, t0, t1, ews, rowsum);
    pv_norm<<<gridM, 256, 0, stream>>>(t2, t3, ews, attn, rowsum, out);
  } else if (ws_size >= rowsum_bytes + e_bytes + 2 * tile_bytes) {
    // 571.0 MB: time-shared tile buffer.
    prep_k_kernel<<<gridP, 256, 0, stream>>>(kr, ki, t0, t1);
    qk_ews<<<gridM, 256, 0, stream>>>(qr, qi, t0, t1, ews, rowsum);
    prep_v_kernel<<<gridP, 256, 0, stream>>>(vr, vi, t0, t1);
    pv_norm<<<gridM, 256, 0, stream>>>(t0, t1, ews, attn, rowsum, out);
  } else {
    qk_exp_legacy<<<gridM, 256, 0, stream>>>(qr, qi, kr, ki, attn, rowsum);
    pv_legacy<<<gridM, 256, 0, stream>>>(vr, vi, attn, rowsum, out);
  }
}